// Round 11
// baseline (40.614 us; speedup 1.0000x reference)
//
#include <hip/hip_runtime.h>

// ---------------------------------------------------------------------------
// Hopfield block, B=131072 independent problems of S=14, D=16 -> softmax(7).
// One batch spread over all 64 lanes; every reduction is an MFMA.
// THIS ROUND: global_load_lds DMA staging. Each wave stages 8 batches
// (7168 B) with 7 width-16 DMA instructions (no VGPR round trip), source
// pre-permuted so LDS layout [b][q][row] gives ~conflict-free ds_read_b128
// and pad lanes become same-address broadcasts. Counted vmcnt(3)/vmcnt(0)
// gates batches 0-3 / 4-7; stores happen after all waits.
//   stats: mean,Ex2 = mfma(1/16, x)         (reduce d, broadcast)
//   T  = mfma(MT*L2E, xh, C=r*L2E)          (score projection, log2-scaled)
//   SS = mfma(xh, T)                        (scores^T, log2 units)
//   P  = mfma(xh, W2T)                      (P[key][c], key in regs)
//   E  = exp2(SS)        Zt = mfma(E, ONES) (Z_s lands in the REG dim)
//   G' = mfma(E, P)                         (unnormalized output)
//   z  = mfma(wm*L2E/Z, G', C=const2*L2E)   (normalization folded in here)
// ---------------------------------------------------------------------------

#define NBATCH 131072
#define NWAVE  16384          // 8 batches per wave
#define NBLK   (NWAVE / 4)    // 4096 blocks x 4 waves

typedef float    f32x4 __attribute__((ext_vector_type(4)));
typedef _Float16 f16x4 __attribute__((ext_vector_type(4)));
typedef __fp16   h16x2 __attribute__((ext_vector_type(2)));

#define ROR(x,N) __int_as_float(__builtin_amdgcn_update_dpp(0, __float_as_int(x), 0x120 + (N), 0xF, 0xF, false))

static __device__ __forceinline__ f16x4 cvt4(float a, float b, float c, float d) {
    union { f16x4 v; h16x2 h[2]; } u;
    u.h[0] = __builtin_amdgcn_cvt_pkrtz(a, b);
    u.h[1] = __builtin_amdgcn_cvt_pkrtz(c, d);
    return u.v;
}

static __device__ __forceinline__ f32x4 mfma16(f16x4 a, f16x4 b, f32x4 c) {
#if __has_builtin(__builtin_amdgcn_mfma_f32_16x16x16f16)
    return __builtin_amdgcn_mfma_f32_16x16x16f16(a, b, c, 0, 0, 0);
#else
    f32x4 d;
    asm("v_mfma_f32_16x16x16_f16 %0, %1, %2, %3" : "=v"(d) : "v"(a), "v"(b), "v"(c));
    return d;
#endif
}

// ---------------------------------------------------------------------------
// Pre-kernel: fold weights into ws (all f32). L2E = log2(e) pre-baked into
// MT, r, wm, const2 so the main kernel uses exp2 directly with no scaling.
//   ws[  0..255]  MT[dd][d]*L2E   (M = Wq'^T Wk', Wx' = g_x (.) Wx)
//   ws[256..271]  r[dd]*L2E       (r = bq'^T Wk', bq' = bq + Wq@b_lnq)
//   ws[272..527]  W2pad[c][d] 16x16, rows c=7..15 zero;  W2 = (Wb@Wo)@Wv'
//   ws[528..543]  const2[c]*L2E (c<7), zero-padded
//   ws[544..559]  wm[s]*L2E (s<14), zero-padded
// ---------------------------------------------------------------------------
__global__ __launch_bounds__(256) void hop_prep(
    const float* __restrict__ gq, const float* __restrict__ bq_ln,
    const float* __restrict__ gk,
    const float* __restrict__ gv, const float* __restrict__ bv_ln,
    const float* __restrict__ Wq, const float* __restrict__ bq,
    const float* __restrict__ Wk,
    const float* __restrict__ Wv, const float* __restrict__ bv,
    const float* __restrict__ Wo, const float* __restrict__ bo,
    const float* __restrict__ Wm, const float* __restrict__ bm,
    const float* __restrict__ Wb, const float* __restrict__ bb,
    float* __restrict__ ws)
{
    const float L2E = 1.4426950408889634f;
    __shared__ float WqP[256], WkP[256], WvP[256];
    __shared__ float bqP[16], bvP[16], WcS[112];
    const int t = threadIdx.x;
    {
        const int d = t & 15;
        WqP[t] = Wq[t] * gq[d];
        WkP[t] = Wk[t] * gk[d];
        WvP[t] = Wv[t] * gv[d];
    }
    if (t < 16) {
        float a = bq[t], c = bv[t];
        for (int d = 0; d < 16; ++d) {
            a = fmaf(Wq[t*16+d], bq_ln[d], a);
            c = fmaf(Wv[t*16+d], bv_ln[d], c);
        }
        bqP[t] = a; bvP[t] = c;
    }
    if (t < 112) {   // Wc = Wb@Wo (7x16), depends only on globals
        const int c = t >> 4, e = t & 15;
        float s = 0.f;
        for (int o = 0; o < 128; ++o) s = fmaf(Wb[c*128+o], Wo[o*16+e], s);
        WcS[t] = s;
    }
    __syncthreads();
    {   // MT (transposed M), log2-scaled: ws[dd*16+d] = M[d][dd]*L2E
        const int dd = t >> 4, d = t & 15;
        float m = 0.f;
        for (int e = 0; e < 16; ++e) m = fmaf(WqP[e*16+d], WkP[e*16+dd], m);
        ws[t] = m * L2E;
    }
    if (t < 16) {
        float rr = 0.f;
        for (int e = 0; e < 16; ++e) rr = fmaf(bqP[e], WkP[e*16+t], rr);
        ws[256 + t] = rr * L2E;
    }
    {   // W2pad: 16x16, rows c>=7 zero
        const int c = t >> 4, d = t & 15;
        float s = 0.f;
        if (c < 7)
            for (int e = 0; e < 16; ++e) s = fmaf(WcS[c*16+e], WvP[e*16+d], s);
        ws[272 + t] = s;
    }
    if (t < 16) {
        float v = 0.f;
        if (t < 7) {
            float wmsum = 0.f;
            for (int s = 0; s < 14; ++s) wmsum += Wm[s];
            float s1 = 0.f;
            for (int e = 0; e < 16; ++e) s1 = fmaf(WcS[t*16+e], bvP[e], s1);
            float s2 = 0.f, s3 = 0.f;
            for (int o = 0; o < 128; ++o) { s2 = fmaf(Wb[t*128+o], bo[o], s2); s3 += Wb[t*128+o]; }
            v = wmsum*s1 + wmsum*s2 + bm[0]*s3 + bb[t];
        }
        ws[528 + t] = v * L2E;
        ws[544 + t] = (t < 14) ? Wm[t] * L2E : 0.0f;
    }
}

// ---------------------------------------------------------------------------
// Main kernel. Fragment convention (v_mfma_f32_16x16x16_f16), lane l:
//   col=l&15, q=l>>4;  A[m=col][k=4q+i]  B[k=4q+i][n=col]  D[m=4q+i][n=col]
// LDS layout per wave (7168 B): 16B chunk index p = b*56 + q*14 + row.
// DMA instruction j writes LDS positions p = j*64 + lane (linear), so the
// global source for (j,lane) is the chunk (b,q,row) decoded from p.
// ---------------------------------------------------------------------------
__global__ __launch_bounds__(256, 8) void hop_main(const float* __restrict__ smp,
                                                   const float* __restrict__ W,
                                                   float* __restrict__ out)
{
    __shared__ __align__(16) char lds[4 * 7168];
    const int wave = (blockIdx.x * 256 + threadIdx.x) >> 6;   // 0..NWAVE-1
    const int wsl  = threadIdx.x >> 6;                        // wave slot
    const int l    = threadIdx.x & 63;
    const int col  = l & 15;
    const int q    = l >> 4;

    // one-time constant fragments (cached loads: reused by every block)
    const float4 mt  = *reinterpret_cast<const float4*>(W + col*16 + q*4);
    const float4 w2  = *reinterpret_cast<const float4*>(W + 272 + col*16 + q*4);
    const float4 r4  = *reinterpret_cast<const float4*>(W + 256 + q*4);
    const float4 wm4 = *reinterpret_cast<const float4*>(W + 544 + q*4);
    const float  c2_l = W[528 + col];
    const f16x4 mtA  = cvt4(mt.x, mt.y, mt.z, mt.w);
    const f16x4 w2B  = cvt4(w2.x, w2.y, w2.z, w2.w);
    const f16x4 ONE  = {(_Float16)1.0f, (_Float16)1.0f, (_Float16)1.0f, (_Float16)1.0f};
    const f16x4 SIXT = {(_Float16)0.0625f, (_Float16)0.0625f, (_Float16)0.0625f, (_Float16)0.0625f};
    const f32x4 zero = {0.f, 0.f, 0.f, 0.f};
    const f32x4 rC   = {r4.x, r4.y, r4.z, r4.w};
    const f32x4 c2C  = {c2_l, c2_l, c2_l, c2_l};
    const bool  hi   = (q == 3);

    // per-thread LDS read offset: chunk (b, q, srow) at (b*56 + q*14 + srow)*16
    const int srow = (col < 14) ? col : 13;                  // clamp pad rows
    char* lw = lds + wsl * 7168;
    const int ldsoff = (q * 14 + srow) * 16;

    // per-lane DMA source offsets: decode LDS position p = j*64+l -> (b,q,row)
    int off[7];
    #pragma unroll
    for (int j = 0; j < 7; ++j) {
        const int p   = j * 64 + l;          // 0..447
        const int b   = p / 56;              // batch 0..7
        const int rem = p - b * 56;          // 0..55
        const int qq  = rem / 14;            // 0..3
        const int rr  = rem - qq * 14;       // row 0..13
        off[j] = b * 896 + rr * 64 + qq * 16;  // byte offset in wave chunk
    }
    const char* gw = reinterpret_cast<const char*>(smp) + (size_t)wave * 7168;

    // drain constant loads so vmcnt counts exactly our 7 DMA ops
    asm volatile("s_waitcnt vmcnt(0)" ::: "memory");
    #pragma unroll
    for (int j = 0; j < 7; ++j) {
        __builtin_amdgcn_global_load_lds(
            (const __attribute__((address_space(1))) void*)(gw + off[j]),
            (__attribute__((address_space(3))) void*)(lw + j * 1024),
            16, 0, 0);
    }

    auto zbatch = [&](int b) -> float {
        const f32x4 x = *reinterpret_cast<const f32x4*>(lw + b * 896 + ldsoff);
        // LN stats via reduce-MFMAs (replicated per row)
        const f16x4 xf  = cvt4(x[0], x[1], x[2], x[3]);
        const f16x4 xqf = cvt4(x[0]*x[0], x[1]*x[1], x[2]*x[2], x[3]*x[3]);
        const f32x4 S1 = mfma16(SIXT, xf,  zero);
        const f32x4 S2 = mfma16(SIXT, xqf, zero);
        const float mean = S1[0];
        const float var  = fmaf(-mean, mean, S2[0]);
        const float rstd = __builtin_amdgcn_rsqf(var + 1e-5f);
        const float nmr  = -mean * rstd;
        const f16x4 xhA = cvt4(fmaf(x[0], rstd, nmr), fmaf(x[1], rstd, nmr),
                               fmaf(x[2], rstd, nmr), fmaf(x[3], rstd, nmr));
        // P[key][c] (key in regs) -- independent branch
        const f32x4 P = mfma16(xhA, w2B, zero);
        // T = MT@xh^T + r (log2-scaled), then scores^T (log2 units)
        const f32x4 T  = mfma16(mtA, xhA, rC);
        const f16x4 B2 = cvt4(T[0], T[1], T[2], T[3]);
        const f32x4 SS = mfma16(xhA, B2, zero);
        // exp2 (scores bounded, no max subtraction); kill pad keys 14,15
        const float e0 = __builtin_amdgcn_exp2f(SS[0]);
        const float e1 = __builtin_amdgcn_exp2f(SS[1]);
        const float e2 = hi ? 0.0f : __builtin_amdgcn_exp2f(SS[2]);
        const float e3 = hi ? 0.0f : __builtin_amdgcn_exp2f(SS[3]);
        const f16x4 E  = cvt4(e0, e1, e2, e3);
        const f16x4 Pf = cvt4(P[0], P[1], P[2], P[3]);
        // Zt: E fed as A transposes the reduce -> Z_s lands in the REG dim
        const f32x4 Zt = mfma16(E, ONE, zero);
        const f32x4 G  = mfma16(E, Pf,  zero);    // unnormalized output
        const float w0 = wm4.x * __builtin_amdgcn_rcpf(Zt[0]);
        const float w1 = wm4.y * __builtin_amdgcn_rcpf(Zt[1]);
        const float w2s = wm4.z * __builtin_amdgcn_rcpf(Zt[2]);
        const float w3 = wm4.w * __builtin_amdgcn_rcpf(Zt[3]);
        const f16x4 wA = cvt4(w0, w1, w2s, w3);
        const f16x4 Gf = cvt4(G[0], G[1], G[2], G[3]);
        // z_c = sum_s (wm_s/Z_s) G'[s][c] + const2_c  (log2-scaled)
        const f32x4 ZZ = mfma16(wA, Gf, c2C);
        return ZZ[0];
    };

    // batches 0-3 ready after the oldest 4 DMA ops (positions 0..255 cover
    // chunks of b=0..3 entirely: b*56+... <= 223 < 256)
    asm volatile("s_waitcnt vmcnt(3)" ::: "memory");
    const float z0 = zbatch(0);
    __builtin_amdgcn_sched_barrier(0);
    const float z1 = zbatch(1);
    __builtin_amdgcn_sched_barrier(0);
    const float z2 = zbatch(2);
    __builtin_amdgcn_sched_barrier(0);
    const float z3 = zbatch(3);
    asm volatile("s_waitcnt vmcnt(0)" ::: "memory");
    const float z4 = zbatch(4);
    __builtin_amdgcn_sched_barrier(0);
    const float z5 = zbatch(5);
    __builtin_amdgcn_sched_barrier(0);
    const float z6 = zbatch(6);
    __builtin_amdgcn_sched_barrier(0);
    const float z7 = zbatch(7);

    // shared softmax7 epilogues: lane-group q handles batch base+q
    auto epilogue = [&](float a0, float a1, float a2, float a3, float* o) {
        float z = (q == 1) ? a1 : a0;
        z = (q == 2) ? a2 : z;
        z = (q == 3) ? a3 : z;
        float e = (col < 7) ? __builtin_amdgcn_exp2f(z) : 0.0f;
        float s = e;
        s += ROR(s, 1); s += ROR(s, 2); s += ROR(s, 4); s += ROR(s, 8);
        if (col < 7) *o = e * __builtin_amdgcn_rcpf(s);
    };
    float* ob = out + ((size_t)wave * 8 + q) * 7 + col;
    epilogue(z0, z1, z2, z3, ob);
    epilogue(z4, z5, z6, z7, ob + 28);

}

extern "C" void kernel_launch(void* const* d_in, const int* in_sizes, int n_in,
                              void* d_out, int out_size, void* d_ws, size_t ws_size,
                              hipStream_t stream) {
    (void)in_sizes; (void)n_in; (void)out_size; (void)ws_size;
    const float* smp = (const float*)d_in[0];
    float* ws = (float*)d_ws;
    hop_prep<<<1, 256, 0, stream>>>(
        (const float*)d_in[1],  (const float*)d_in[2],   // ln_q_g, ln_q_b
        (const float*)d_in[3],                           // ln_k_g
        (const float*)d_in[5],  (const float*)d_in[6],   // ln_v_g, ln_v_b
        (const float*)d_in[7],  (const float*)d_in[8],   // Wq, bq
        (const float*)d_in[9],                           // Wk
        (const float*)d_in[11], (const float*)d_in[12],  // Wv, bv
        (const float*)d_in[13], (const float*)d_in[14],  // Wo, bo
        (const float*)d_in[15], (const float*)d_in[16],  // Wm, bm
        (const float*)d_in[17], (const float*)d_in[18],  // Wb, bb
        ws);
    hop_main<<<NBLK, 256, 0, stream>>>(smp, ws, (float*)d_out);
}

// Round 12
// 38.218 us; speedup vs baseline: 1.0627x; 1.0627x over previous
//
#include <hip/hip_runtime.h>

// ---------------------------------------------------------------------------
// Hopfield block, B=131072 independent problems of S=14, D=16 -> softmax(7).
// One batch spread over all 64 lanes; every reduction is an MFMA.
// THIS ROUND: TLP-first. 2 batches per wave (was 4), 65536 waves, no
// sched_barrier between the two chains (compiler interleaves for ILP).
// Short per-wave dependency chain + low VGPR (<64) + 8 waves/SIMD.
//   stats: mean,Ex2 = mfma(1/16, x)         (reduce d, broadcast)
//   T  = mfma(MT*L2E, xh, C=r*L2E)          (score projection, log2-scaled)
//   SS = mfma(xh, T)                        (scores^T, log2 units)
//   P  = mfma(xh, W2T)                      (P[key][c], key in regs)
//   E  = exp2(SS)        Zt = mfma(E, ONES) (Z_s lands in the REG dim)
//   G' = mfma(E, P)                         (unnormalized output)
//   z  = mfma(wm*L2E/Z, G', C=const2*L2E)   (normalization folded in here)
// ---------------------------------------------------------------------------

#define NBATCH 131072
#define NWAVE  (NBATCH / 2)       // 2 batches per wave
#define NBLK   (NWAVE * 64 / 256) // 16384 blocks

typedef float    f32x4 __attribute__((ext_vector_type(4)));
typedef _Float16 f16x4 __attribute__((ext_vector_type(4)));
typedef __fp16   h16x2 __attribute__((ext_vector_type(2)));

#define ROR(x,N) __int_as_float(__builtin_amdgcn_update_dpp(0, __float_as_int(x), 0x120 + (N), 0xF, 0xF, false))

static __device__ __forceinline__ f16x4 cvt4(float a, float b, float c, float d) {
    union { f16x4 v; h16x2 h[2]; } u;
    u.h[0] = __builtin_amdgcn_cvt_pkrtz(a, b);
    u.h[1] = __builtin_amdgcn_cvt_pkrtz(c, d);
    return u.v;
}

static __device__ __forceinline__ f32x4 mfma16(f16x4 a, f16x4 b, f32x4 c) {
#if __has_builtin(__builtin_amdgcn_mfma_f32_16x16x16f16)
    return __builtin_amdgcn_mfma_f32_16x16x16f16(a, b, c, 0, 0, 0);
#else
    f32x4 d;
    asm("v_mfma_f32_16x16x16_f16 %0, %1, %2, %3" : "=v"(d) : "v"(a), "v"(b), "v"(c));
    return d;
#endif
}

// ---------------------------------------------------------------------------
// Pre-kernel: fold weights into ws (all f32). L2E = log2(e) pre-baked into
// MT, r, wm, const2 so the main kernel uses exp2 directly with no scaling.
//   ws[  0..255]  MT[dd][d]*L2E   (M = Wq'^T Wk', Wx' = g_x (.) Wx)
//   ws[256..271]  r[dd]*L2E       (r = bq'^T Wk', bq' = bq + Wq@b_lnq)
//   ws[272..527]  W2pad[c][d] 16x16, rows c=7..15 zero;  W2 = (Wb@Wo)@Wv'
//   ws[528..543]  const2[c]*L2E (c<7), zero-padded
//   ws[544..559]  wm[s]*L2E (s<14), zero-padded
// ---------------------------------------------------------------------------
__global__ __launch_bounds__(256) void hop_prep(
    const float* __restrict__ gq, const float* __restrict__ bq_ln,
    const float* __restrict__ gk,
    const float* __restrict__ gv, const float* __restrict__ bv_ln,
    const float* __restrict__ Wq, const float* __restrict__ bq,
    const float* __restrict__ Wk,
    const float* __restrict__ Wv, const float* __restrict__ bv,
    const float* __restrict__ Wo, const float* __restrict__ bo,
    const float* __restrict__ Wm, const float* __restrict__ bm,
    const float* __restrict__ Wb, const float* __restrict__ bb,
    float* __restrict__ ws)
{
    const float L2E = 1.4426950408889634f;
    __shared__ float WqP[256], WkP[256], WvP[256];
    __shared__ float bqP[16], bvP[16], WcS[112];
    const int t = threadIdx.x;
    {
        const int d = t & 15;
        WqP[t] = Wq[t] * gq[d];
        WkP[t] = Wk[t] * gk[d];
        WvP[t] = Wv[t] * gv[d];
    }
    if (t < 16) {
        float a = bq[t], c = bv[t];
        for (int d = 0; d < 16; ++d) {
            a = fmaf(Wq[t*16+d], bq_ln[d], a);
            c = fmaf(Wv[t*16+d], bv_ln[d], c);
        }
        bqP[t] = a; bvP[t] = c;
    }
    if (t < 112) {   // Wc = Wb@Wo (7x16), depends only on globals
        const int c = t >> 4, e = t & 15;
        float s = 0.f;
        for (int o = 0; o < 128; ++o) s = fmaf(Wb[c*128+o], Wo[o*16+e], s);
        WcS[t] = s;
    }
    __syncthreads();
    {   // MT (transposed M), log2-scaled: ws[dd*16+d] = M[d][dd]*L2E
        const int dd = t >> 4, d = t & 15;
        float m = 0.f;
        for (int e = 0; e < 16; ++e) m = fmaf(WqP[e*16+d], WkP[e*16+dd], m);
        ws[t] = m * L2E;
    }
    if (t < 16) {
        float rr = 0.f;
        for (int e = 0; e < 16; ++e) rr = fmaf(bqP[e], WkP[e*16+t], rr);
        ws[256 + t] = rr * L2E;
    }
    {   // W2pad: 16x16, rows c>=7 zero
        const int c = t >> 4, d = t & 15;
        float s = 0.f;
        if (c < 7)
            for (int e = 0; e < 16; ++e) s = fmaf(WcS[c*16+e], WvP[e*16+d], s);
        ws[272 + t] = s;
    }
    if (t < 16) {
        float v = 0.f;
        if (t < 7) {
            float wmsum = 0.f;
            for (int s = 0; s < 14; ++s) wmsum += Wm[s];
            float s1 = 0.f;
            for (int e = 0; e < 16; ++e) s1 = fmaf(WcS[t*16+e], bvP[e], s1);
            float s2 = 0.f, s3 = 0.f;
            for (int o = 0; o < 128; ++o) { s2 = fmaf(Wb[t*128+o], bo[o], s2); s3 += Wb[t*128+o]; }
            v = wmsum*s1 + wmsum*s2 + bm[0]*s3 + bb[t];
        }
        ws[528 + t] = v * L2E;
        ws[544 + t] = (t < 14) ? Wm[t] * L2E : 0.0f;
    }
}

// ---------------------------------------------------------------------------
// Main kernel. Fragment convention (v_mfma_f32_16x16x16_f16), lane l:
//   col=l&15, q=l>>4;  A[m=col][k=4q+i]  B[k=4q+i][n=col]  D[m=4q+i][n=col]
// 2 batches per wave; both chains live concurrently (ILP), VGPR target <64
// so 8 waves/SIMD stay resident (the latency-hiding lever).
// ---------------------------------------------------------------------------
__global__ __launch_bounds__(256, 8) void hop_main(const float* __restrict__ smp,
                                                   const float* __restrict__ W,
                                                   float* __restrict__ out)
{
    const int wave = (blockIdx.x * 256 + threadIdx.x) >> 6;   // 0..NWAVE-1
    const int l    = threadIdx.x & 63;
    const int col  = l & 15;
    const int q    = l >> 4;

    // one-time constant fragments (cached loads: reused by every block)
    const float4 mt  = *reinterpret_cast<const float4*>(W + col*16 + q*4);
    const float4 w2  = *reinterpret_cast<const float4*>(W + 272 + col*16 + q*4);
    const float4 r4  = *reinterpret_cast<const float4*>(W + 256 + q*4);
    const float4 wm4 = *reinterpret_cast<const float4*>(W + 544 + q*4);
    const float  c2_l = W[528 + col];
    const f16x4 mtA  = cvt4(mt.x, mt.y, mt.z, mt.w);
    const f16x4 w2B  = cvt4(w2.x, w2.y, w2.z, w2.w);
    const f16x4 ONE  = {(_Float16)1.0f, (_Float16)1.0f, (_Float16)1.0f, (_Float16)1.0f};
    const f16x4 SIXT = {(_Float16)0.0625f, (_Float16)0.0625f, (_Float16)0.0625f, (_Float16)0.0625f};
    const f32x4 zero = {0.f, 0.f, 0.f, 0.f};
    const f32x4 rC   = {r4.x, r4.y, r4.z, r4.w};
    const f32x4 c2C  = {c2_l, c2_l, c2_l, c2_l};
    const bool  hi   = (q == 3);

    const int srow = (col < 14) ? col : 13;                  // clamp pad rows
    const float* p0 = smp + (size_t)wave * 448 + srow * 16 + q * 4;

    auto zbatch = [&](const f32x4& x) -> float {
        // LN stats via reduce-MFMAs (replicated per row)
        const f16x4 xf  = cvt4(x[0], x[1], x[2], x[3]);
        const f16x4 xqf = cvt4(x[0]*x[0], x[1]*x[1], x[2]*x[2], x[3]*x[3]);
        const f32x4 S1 = mfma16(SIXT, xf,  zero);
        const f32x4 S2 = mfma16(SIXT, xqf, zero);
        const float mean = S1[0];
        const float var  = fmaf(-mean, mean, S2[0]);
        const float rstd = __builtin_amdgcn_rsqf(var + 1e-5f);
        const float nmr  = -mean * rstd;
        const f16x4 xhA = cvt4(fmaf(x[0], rstd, nmr), fmaf(x[1], rstd, nmr),
                               fmaf(x[2], rstd, nmr), fmaf(x[3], rstd, nmr));
        // P[key][c] (key in regs) -- independent branch
        const f32x4 P = mfma16(xhA, w2B, zero);
        // T = MT@xh^T + r (log2-scaled), then scores^T (log2 units)
        const f32x4 T  = mfma16(mtA, xhA, rC);
        const f16x4 B2 = cvt4(T[0], T[1], T[2], T[3]);
        const f32x4 SS = mfma16(xhA, B2, zero);
        // exp2 (scores bounded, no max subtraction); kill pad keys 14,15
        const float e0 = __builtin_amdgcn_exp2f(SS[0]);
        const float e1 = __builtin_amdgcn_exp2f(SS[1]);
        const float e2 = hi ? 0.0f : __builtin_amdgcn_exp2f(SS[2]);
        const float e3 = hi ? 0.0f : __builtin_amdgcn_exp2f(SS[3]);
        const f16x4 E  = cvt4(e0, e1, e2, e3);
        const f16x4 Pf = cvt4(P[0], P[1], P[2], P[3]);
        // Zt: E fed as A transposes the reduce -> Z_s lands in the REG dim
        const f32x4 Zt = mfma16(E, ONE, zero);
        const f32x4 G  = mfma16(E, Pf,  zero);    // unnormalized output
        const float w0 = wm4.x * __builtin_amdgcn_rcpf(Zt[0]);
        const float w1 = wm4.y * __builtin_amdgcn_rcpf(Zt[1]);
        const float w2s = wm4.z * __builtin_amdgcn_rcpf(Zt[2]);
        const float w3 = wm4.w * __builtin_amdgcn_rcpf(Zt[3]);
        const f16x4 wA = cvt4(w0, w1, w2s, w3);
        const f16x4 Gf = cvt4(G[0], G[1], G[2], G[3]);
        // z_c = sum_s (wm_s/Z_s) G'[s][c] + const2_c  (log2-scaled)
        const f32x4 ZZ = mfma16(wA, Gf, c2C);
        return ZZ[0];
    };

    // both batch loads hoisted (NT, streaming); both chains interleave (ILP)
    const f32x4 a0 = __builtin_nontemporal_load(reinterpret_cast<const f32x4*>(p0));
    const f32x4 a1 = __builtin_nontemporal_load(reinterpret_cast<const f32x4*>(p0 + 224));

    const float z0 = zbatch(a0);
    const float z1 = zbatch(a1);

    // shared softmax7: lane-group q=0 -> batch wave*2, q=1 -> wave*2+1
    float z = (q & 1) ? z1 : z0;
    float e = (col < 7) ? __builtin_amdgcn_exp2f(z) : 0.0f;
    float s = e;
    s += ROR(s, 1); s += ROR(s, 2); s += ROR(s, 4); s += ROR(s, 8);
    if (q < 2 && col < 7)
        __builtin_nontemporal_store(e * __builtin_amdgcn_rcpf(s),
                                    out + ((size_t)wave * 2 + q) * 7 + col);
}

extern "C" void kernel_launch(void* const* d_in, const int* in_sizes, int n_in,
                              void* d_out, int out_size, void* d_ws, size_t ws_size,
                              hipStream_t stream) {
    (void)in_sizes; (void)n_in; (void)out_size; (void)ws_size;
    const float* smp = (const float*)d_in[0];
    float* ws = (float*)d_ws;
    hop_prep<<<1, 256, 0, stream>>>(
        (const float*)d_in[1],  (const float*)d_in[2],   // ln_q_g, ln_q_b
        (const float*)d_in[3],                           // ln_k_g
        (const float*)d_in[5],  (const float*)d_in[6],   // ln_v_g, ln_v_b
        (const float*)d_in[7],  (const float*)d_in[8],   // Wq, bq
        (const float*)d_in[9],                           // Wk
        (const float*)d_in[11], (const float*)d_in[12],  // Wv, bv
        (const float*)d_in[13], (const float*)d_in[14],  // Wo, bo
        (const float*)d_in[15], (const float*)d_in[16],  // Wm, bm
        (const float*)d_in[17], (const float*)d_in[18],  // Wb, bb
        ws);
    hop_main<<<NBLK, 256, 0, stream>>>(smp, ws, (float*)d_out);
}

// Round 13
// 34.048 us; speedup vs baseline: 1.1928x; 1.1225x over previous
//
#include <hip/hip_runtime.h>

// ---------------------------------------------------------------------------
// Hopfield block, B=131072 independent problems of S=14, D=16 -> softmax(7).
// One batch spread over all 64 lanes. MFMA only for real matmuls (4/batch):
//   T  = mfma(MT*L2E, xh, C=r*L2E)   score projection (log2-scaled)
//   SS = mfma(xh, T)                 scores^T: SS[k=4q+i][s=col]
//   P  = mfma(xh, W2T)               P[key=4q+i][c=col]
//   G  = mfma((wm_s/Z_s)E^T, P)      weighted PV: G[s=4q+i][c=col]
// All small reductions (LN stats, Z, z) are f32 adds + shfl_xor(16/32).
// Z lands per-col (col=s) -> ONE rcp per batch. Register-lean by design:
// ~50 VGPR live so __launch_bounds__(256,8) holds WITHOUT spilling.
// ---------------------------------------------------------------------------

#define NBATCH 131072

typedef float    f32x4 __attribute__((ext_vector_type(4)));
typedef _Float16 f16x4 __attribute__((ext_vector_type(4)));
typedef __fp16   h16x2 __attribute__((ext_vector_type(2)));

#define ROR(x,N) __int_as_float(__builtin_amdgcn_update_dpp(0, __float_as_int(x), 0x120 + (N), 0xF, 0xF, false))

static __device__ __forceinline__ f16x4 cvt4(float a, float b, float c, float d) {
    union { f16x4 v; h16x2 h[2]; } u;
    u.h[0] = __builtin_amdgcn_cvt_pkrtz(a, b);
    u.h[1] = __builtin_amdgcn_cvt_pkrtz(c, d);
    return u.v;
}

static __device__ __forceinline__ f32x4 mfma16(f16x4 a, f16x4 b, f32x4 c) {
#if __has_builtin(__builtin_amdgcn_mfma_f32_16x16x16f16)
    return __builtin_amdgcn_mfma_f32_16x16x16f16(a, b, c, 0, 0, 0);
#else
    f32x4 d;
    asm("v_mfma_f32_16x16x16_f16 %0, %1, %2, %3" : "=v"(d) : "v"(a), "v"(b), "v"(c));
    return d;
#endif
}

// ---------------------------------------------------------------------------
// Pre-kernel: fold weights into ws (all f32). L2E = log2(e) pre-baked into
// MT, r, wm, const2 so the main kernel uses exp2 directly with no scaling.
//   ws[  0..255]  MT[dd][d]*L2E   (M = Wq'^T Wk', Wx' = g_x (.) Wx)
//   ws[256..271]  r[dd]*L2E       (r = bq'^T Wk', bq' = bq + Wq@b_lnq)
//   ws[272..527]  W2pad[c][d] 16x16, rows c=7..15 zero;  W2 = (Wb@Wo)@Wv'
//   ws[528..543]  const2[c]*L2E (c<7), zero-padded
//   ws[544..559]  wm[s]*L2E (s<14), zero-padded
// ---------------------------------------------------------------------------
__global__ __launch_bounds__(256) void hop_prep(
    const float* __restrict__ gq, const float* __restrict__ bq_ln,
    const float* __restrict__ gk,
    const float* __restrict__ gv, const float* __restrict__ bv_ln,
    const float* __restrict__ Wq, const float* __restrict__ bq,
    const float* __restrict__ Wk,
    const float* __restrict__ Wv, const float* __restrict__ bv,
    const float* __restrict__ Wo, const float* __restrict__ bo,
    const float* __restrict__ Wm, const float* __restrict__ bm,
    const float* __restrict__ Wb, const float* __restrict__ bb,
    float* __restrict__ ws)
{
    const float L2E = 1.4426950408889634f;
    __shared__ float WqP[256], WkP[256], WvP[256];
    __shared__ float bqP[16], bvP[16], WcS[112];
    const int t = threadIdx.x;
    {
        const int d = t & 15;
        WqP[t] = Wq[t] * gq[d];
        WkP[t] = Wk[t] * gk[d];
        WvP[t] = Wv[t] * gv[d];
    }
    if (t < 16) {
        float a = bq[t], c = bv[t];
        for (int d = 0; d < 16; ++d) {
            a = fmaf(Wq[t*16+d], bq_ln[d], a);
            c = fmaf(Wv[t*16+d], bv_ln[d], c);
        }
        bqP[t] = a; bvP[t] = c;
    }
    if (t < 112) {   // Wc = Wb@Wo (7x16), depends only on globals
        const int c = t >> 4, e = t & 15;
        float s = 0.f;
        for (int o = 0; o < 128; ++o) s = fmaf(Wb[c*128+o], Wo[o*16+e], s);
        WcS[t] = s;
    }
    __syncthreads();
    {   // MT (transposed M), log2-scaled: ws[dd*16+d] = M[d][dd]*L2E
        const int dd = t >> 4, d = t & 15;
        float m = 0.f;
        for (int e = 0; e < 16; ++e) m = fmaf(WqP[e*16+d], WkP[e*16+dd], m);
        ws[t] = m * L2E;
    }
    if (t < 16) {
        float rr = 0.f;
        for (int e = 0; e < 16; ++e) rr = fmaf(bqP[e], WkP[e*16+t], rr);
        ws[256 + t] = rr * L2E;
    }
    {   // W2pad: 16x16, rows c>=7 zero
        const int c = t >> 4, d = t & 15;
        float s = 0.f;
        if (c < 7)
            for (int e = 0; e < 16; ++e) s = fmaf(WcS[c*16+e], WvP[e*16+d], s);
        ws[272 + t] = s;
    }
    if (t < 16) {
        float v = 0.f;
        if (t < 7) {
            float wmsum = 0.f;
            for (int s = 0; s < 14; ++s) wmsum += Wm[s];
            float s1 = 0.f;
            for (int e = 0; e < 16; ++e) s1 = fmaf(WcS[t*16+e], bvP[e], s1);
            float s2 = 0.f, s3 = 0.f;
            for (int o = 0; o < 128; ++o) { s2 = fmaf(Wb[t*128+o], bo[o], s2); s3 += Wb[t*128+o]; }
            v = wmsum*s1 + wmsum*s2 + bm[0]*s3 + bb[t];
        }
        ws[528 + t] = v * L2E;
        ws[544 + t] = (t < 14) ? Wm[t] * L2E : 0.0f;
    }
}

// ---------------------------------------------------------------------------
// Main kernel. Fragment convention (v_mfma_f32_16x16x16_f16), lane l:
//   col=l&15, q=l>>4;  A[m=col][k=4q+i]  B[k=4q+i][n=col]  D[m=4q+i][n=col]
// A-frag and B-frag share the per-lane layout; a D fed back as A gives the
// transposed contraction. Register-lean: target ~50 live VGPR.
// ---------------------------------------------------------------------------
__global__ __launch_bounds__(256, 8) void hop_main(const float* __restrict__ smp,
                                                   const float* __restrict__ W,
                                                   float* __restrict__ out)
{
    const int wave = (blockIdx.x * 256 + threadIdx.x) >> 6;   // 0..32767
    const int l    = threadIdx.x & 63;
    const int col  = l & 15;
    const int q    = l >> 4;

    // constant fragments: mtA(2) w2B(2) rC(4) zero(4) + 2 scalars
    const float4 mt = *reinterpret_cast<const float4*>(W + col*16 + q*4);
    const float4 w2 = *reinterpret_cast<const float4*>(W + 272 + col*16 + q*4);
    const float4 r4 = *reinterpret_cast<const float4*>(W + 256 + q*4);
    const float wm_l = W[544 + col];       // wm[s]*L2E (0 for pad rows)
    const float c2_l = W[528 + col];       // const2[c]*L2E
    const f16x4 mtA  = cvt4(mt.x, mt.y, mt.z, mt.w);
    const f16x4 w2B  = cvt4(w2.x, w2.y, w2.z, w2.w);
    const f32x4 rC   = {r4.x, r4.y, r4.z, r4.w};
    const f32x4 zero = {0.f, 0.f, 0.f, 0.f};
    const bool  hi   = (q == 3);

    const int srow = (col < 14) ? col : 13;                  // clamp pad rows
    const float* p0 = smp + (size_t)wave * 896 + srow * 16 + q * 4;

    auto zbatch = [&](const f32x4& x) -> float {
        // LN stats: f32 per-lane partials + shfl over the 4 q-groups
        float s1 = (x[0] + x[1]) + (x[2] + x[3]);
        float s2 = fmaf(x[0], x[0], fmaf(x[1], x[1], fmaf(x[2], x[2], x[3]*x[3])));
        s1 += __shfl_xor(s1, 16, 64);  s2 += __shfl_xor(s2, 16, 64);
        s1 += __shfl_xor(s1, 32, 64);  s2 += __shfl_xor(s2, 32, 64);
        const float mean = s1 * 0.0625f;
        const float var  = fmaf(s2, 0.0625f, -mean * mean);
        const float rstd = __builtin_amdgcn_rsqf(var + 1e-5f);
        const float nmr  = -mean * rstd;
        const f16x4 xhA = cvt4(fmaf(x[0], rstd, nmr), fmaf(x[1], rstd, nmr),
                               fmaf(x[2], rstd, nmr), fmaf(x[3], rstd, nmr));
        // P[key][c] (key in regs) -- independent branch
        const f32x4 P = mfma16(xhA, w2B, zero);
        // T = MT@xh^T + r (log2-scaled), then scores^T (log2 units)
        const f32x4 T  = mfma16(mtA, xhA, rC);
        const f16x4 B2 = cvt4(T[0], T[1], T[2], T[3]);
        const f32x4 SS = mfma16(xhA, B2, zero);
        // exp2 (scores bounded, no max subtraction); kill pad keys 14,15
        const float e0 = __builtin_amdgcn_exp2f(SS[0]);
        const float e1 = __builtin_amdgcn_exp2f(SS[1]);
        const float e2 = hi ? 0.0f : __builtin_amdgcn_exp2f(SS[2]);
        const float e3 = hi ? 0.0f : __builtin_amdgcn_exp2f(SS[3]);
        // Z_s at col=s: f32 reduce over k (regs + q-groups); ONE rcp
        float Z = (e0 + e1) + (e2 + e3);
        Z += __shfl_xor(Z, 16, 64);
        Z += __shfl_xor(Z, 32, 64);
        const float f = wm_l * __builtin_amdgcn_rcpf(Z);   // wm_s/Z_s (0 pads)
        // G = (f*E)^T @ P : A[m=s][k=key] = f_s E[key][s]  (E regs ARE E^T)
        const f16x4 EfA = cvt4(e0*f, e1*f, e2*f, e3*f);
        const f16x4 Pf  = cvt4(P[0], P[1], P[2], P[3]);
        const f32x4 G = mfma16(EfA, Pf, zero);             // G[s=4q+i][c=col]
        // z_c = sum_s G + const2: f32 reduce (regs cover s=4q..4q+3)
        float zz = (G[0] + G[1]) + (G[2] + G[3]);
        zz += __shfl_xor(zz, 16, 64);
        zz += __shfl_xor(zz, 32, 64);
        return zz + c2_l;
    };

    // 2-deep NT prefetch; sched_barrier keeps one chain's temps live at a time
    const f32x4 x0 = __builtin_nontemporal_load(reinterpret_cast<const f32x4*>(p0));
    const f32x4 x1 = __builtin_nontemporal_load(reinterpret_cast<const f32x4*>(p0 + 224));
    const float z0 = zbatch(x0);
    __builtin_amdgcn_sched_barrier(0);
    const f32x4 x2 = __builtin_nontemporal_load(reinterpret_cast<const f32x4*>(p0 + 448));
    const float z1 = zbatch(x1);
    __builtin_amdgcn_sched_barrier(0);
    const f32x4 x3 = __builtin_nontemporal_load(reinterpret_cast<const f32x4*>(p0 + 672));
    const float z2 = zbatch(x2);
    __builtin_amdgcn_sched_barrier(0);
    const float z3 = zbatch(x3);

    // shared softmax7: lane-group q handles batch wave*4+q
    float z = (q == 1) ? z1 : z0;
    z = (q == 2) ? z2 : z;
    z = (q == 3) ? z3 : z;
    float e = (col < 7) ? __builtin_amdgcn_exp2f(z) : 0.0f;
    float s = e;
    s += ROR(s, 1); s += ROR(s, 2); s += ROR(s, 4); s += ROR(s, 8);
    if (col < 7)
        __builtin_nontemporal_store(e * __builtin_amdgcn_rcpf(s),
                                    out + ((size_t)wave * 4 + q) * 7 + col);
}

extern "C" void kernel_launch(void* const* d_in, const int* in_sizes, int n_in,
                              void* d_out, int out_size, void* d_ws, size_t ws_size,
                              hipStream_t stream) {
    (void)in_sizes; (void)n_in; (void)out_size; (void)ws_size;
    const float* smp = (const float*)d_in[0];
    float* ws = (float*)d_ws;
    hop_prep<<<1, 256, 0, stream>>>(
        (const float*)d_in[1],  (const float*)d_in[2],   // ln_q_g, ln_q_b
        (const float*)d_in[3],                           // ln_k_g
        (const float*)d_in[5],  (const float*)d_in[6],   // ln_v_g, ln_v_b
        (const float*)d_in[7],  (const float*)d_in[8],   // Wq, bq
        (const float*)d_in[9],                           // Wk
        (const float*)d_in[11], (const float*)d_in[12],  // Wv, bv
        (const float*)d_in[13], (const float*)d_in[14],  // Wo, bo
        (const float*)d_in[15], (const float*)d_in[16],  // Wm, bm
        (const float*)d_in[17], (const float*)d_in[18],  // Wb, bb
        ws);
    hop_main<<<NBATCH * 16 / 256, 256, 0, stream>>>(smp, ws, (float*)d_out);
}

// Round 14
// 30.544 us; speedup vs baseline: 1.3297x; 1.1147x over previous
//
#include <hip/hip_runtime.h>

// ---------------------------------------------------------------------------
// Hopfield block, B=131072 independent problems of S=14, D=16 -> softmax(7).
// One batch spread over all 64 lanes; every reduction is an MFMA (r10-proven).
// THIS ROUND: amortize per-wave fixed cost (launch/drain + W-fragment setup)
// over 8 batches per wave (16384 waves), sched_barrier'd serial chains,
// launch_bounds(256,4) for a 128-VGPR budget (no spill). Prep loops 4-way
// unrolled (prep replays in the graph).
//   stats: mean,Ex2 = mfma(1/16, x)         (reduce d, broadcast)
//   T  = mfma(MT*L2E, xh, C=r*L2E)          (score projection, log2-scaled)
//   SS = mfma(xh, T)                        (scores^T, log2 units)
//   P  = mfma(xh, W2T)                      (P[key][c], key in regs)
//   E  = exp2(SS)        Zt = mfma(E, ONES) (Z_s lands in the REG dim)
//   G' = mfma(E, P)                         (unnormalized output)
//   z  = mfma(wm*L2E/Z, G', C=const2*L2E)   (normalization folded in here)
// ---------------------------------------------------------------------------

#define NBATCH 131072
#define BPW    8                          // batches per wave
#define NWAVE  (NBATCH / BPW)             // 16384 waves
#define NBLK   (NWAVE * 64 / 256)         // 4096 blocks

typedef float    f32x4 __attribute__((ext_vector_type(4)));
typedef _Float16 f16x4 __attribute__((ext_vector_type(4)));
typedef __fp16   h16x2 __attribute__((ext_vector_type(2)));

#define ROR(x,N) __int_as_float(__builtin_amdgcn_update_dpp(0, __float_as_int(x), 0x120 + (N), 0xF, 0xF, false))

static __device__ __forceinline__ f16x4 cvt4(float a, float b, float c, float d) {
    union { f16x4 v; h16x2 h[2]; } u;
    u.h[0] = __builtin_amdgcn_cvt_pkrtz(a, b);
    u.h[1] = __builtin_amdgcn_cvt_pkrtz(c, d);
    return u.v;
}

static __device__ __forceinline__ f32x4 mfma16(f16x4 a, f16x4 b, f32x4 c) {
#if __has_builtin(__builtin_amdgcn_mfma_f32_16x16x16f16)
    return __builtin_amdgcn_mfma_f32_16x16x16f16(a, b, c, 0, 0, 0);
#else
    f32x4 d;
    asm("v_mfma_f32_16x16x16_f16 %0, %1, %2, %3" : "=v"(d) : "v"(a), "v"(b), "v"(c));
    return d;
#endif
}

// ---------------------------------------------------------------------------
// Pre-kernel: fold weights into ws (all f32). L2E = log2(e) pre-baked into
// MT, r, wm, const2 so the main kernel uses exp2 directly with no scaling.
//   ws[  0..255]  MT[dd][d]*L2E   (M = Wq'^T Wk', Wx' = g_x (.) Wx)
//   ws[256..271]  r[dd]*L2E       (r = bq'^T Wk', bq' = bq + Wq@b_lnq)
//   ws[272..527]  W2pad[c][d] 16x16, rows c=7..15 zero;  W2 = (Wb@Wo)@Wv'
//   ws[528..543]  const2[c]*L2E (c<7), zero-padded
//   ws[544..559]  wm[s]*L2E (s<14), zero-padded
// 4-way unrolled reductions: prep replays inside the timed graph.
// ---------------------------------------------------------------------------
__global__ __launch_bounds__(256) void hop_prep(
    const float* __restrict__ gq, const float* __restrict__ bq_ln,
    const float* __restrict__ gk,
    const float* __restrict__ gv, const float* __restrict__ bv_ln,
    const float* __restrict__ Wq, const float* __restrict__ bq,
    const float* __restrict__ Wk,
    const float* __restrict__ Wv, const float* __restrict__ bv,
    const float* __restrict__ Wo, const float* __restrict__ bo,
    const float* __restrict__ Wm, const float* __restrict__ bm,
    const float* __restrict__ Wb, const float* __restrict__ bb,
    float* __restrict__ ws)
{
    const float L2E = 1.4426950408889634f;
    __shared__ float WqP[256], WkP[256], WvP[256];
    __shared__ float bqP[16], bvP[16], WcS[112];
    const int t = threadIdx.x;
    {
        const int d = t & 15;
        WqP[t] = Wq[t] * gq[d];
        WkP[t] = Wk[t] * gk[d];
        WvP[t] = Wv[t] * gv[d];
    }
    if (t < 16) {
        float a0 = bq[t], a1 = 0.f, a2 = 0.f, a3 = 0.f;
        float c0 = bv[t], c1 = 0.f, c2 = 0.f, c3 = 0.f;
        for (int d = 0; d < 16; d += 4) {
            a0 = fmaf(Wq[t*16+d],   bq_ln[d],   a0);
            a1 = fmaf(Wq[t*16+d+1], bq_ln[d+1], a1);
            a2 = fmaf(Wq[t*16+d+2], bq_ln[d+2], a2);
            a3 = fmaf(Wq[t*16+d+3], bq_ln[d+3], a3);
            c0 = fmaf(Wv[t*16+d],   bv_ln[d],   c0);
            c1 = fmaf(Wv[t*16+d+1], bv_ln[d+1], c1);
            c2 = fmaf(Wv[t*16+d+2], bv_ln[d+2], c2);
            c3 = fmaf(Wv[t*16+d+3], bv_ln[d+3], c3);
        }
        bqP[t] = (a0 + a1) + (a2 + a3);
        bvP[t] = (c0 + c1) + (c2 + c3);
    }
    if (t < 112) {   // Wc = Wb@Wo (7x16), 4 independent accumulators
        const int c = t >> 4, e = t & 15;
        float s0 = 0.f, s1 = 0.f, s2 = 0.f, s3 = 0.f;
        for (int o = 0; o < 128; o += 4) {
            s0 = fmaf(Wb[c*128+o],   Wo[o*16+e],     s0);
            s1 = fmaf(Wb[c*128+o+1], Wo[(o+1)*16+e], s1);
            s2 = fmaf(Wb[c*128+o+2], Wo[(o+2)*16+e], s2);
            s3 = fmaf(Wb[c*128+o+3], Wo[(o+3)*16+e], s3);
        }
        WcS[t] = (s0 + s1) + (s2 + s3);
    }
    __syncthreads();
    {   // MT (transposed M), log2-scaled: ws[dd*16+d] = M[d][dd]*L2E
        const int dd = t >> 4, d = t & 15;
        float m0 = 0.f, m1 = 0.f, m2 = 0.f, m3 = 0.f;
        for (int e = 0; e < 16; e += 4) {
            m0 = fmaf(WqP[e*16+d],     WkP[e*16+dd],     m0);
            m1 = fmaf(WqP[(e+1)*16+d], WkP[(e+1)*16+dd], m1);
            m2 = fmaf(WqP[(e+2)*16+d], WkP[(e+2)*16+dd], m2);
            m3 = fmaf(WqP[(e+3)*16+d], WkP[(e+3)*16+dd], m3);
        }
        ws[t] = ((m0 + m1) + (m2 + m3)) * L2E;
    }
    if (t < 16) {
        float r0 = 0.f, r1 = 0.f, r2 = 0.f, r3 = 0.f;
        for (int e = 0; e < 16; e += 4) {
            r0 = fmaf(bqP[e],   WkP[e*16+t],     r0);
            r1 = fmaf(bqP[e+1], WkP[(e+1)*16+t], r1);
            r2 = fmaf(bqP[e+2], WkP[(e+2)*16+t], r2);
            r3 = fmaf(bqP[e+3], WkP[(e+3)*16+t], r3);
        }
        ws[256 + t] = ((r0 + r1) + (r2 + r3)) * L2E;
    }
    {   // W2pad: 16x16, rows c>=7 zero
        const int c = t >> 4, d = t & 15;
        float s = 0.f;
        if (c < 7) {
            float s0 = 0.f, s1 = 0.f, s2 = 0.f, s3 = 0.f;
            for (int e = 0; e < 16; e += 4) {
                s0 = fmaf(WcS[c*16+e],   WvP[e*16+d],     s0);
                s1 = fmaf(WcS[c*16+e+1], WvP[(e+1)*16+d], s1);
                s2 = fmaf(WcS[c*16+e+2], WvP[(e+2)*16+d], s2);
                s3 = fmaf(WcS[c*16+e+3], WvP[(e+3)*16+d], s3);
            }
            s = (s0 + s1) + (s2 + s3);
        }
        ws[272 + t] = s;
    }
    if (t < 16) {
        float v = 0.f;
        if (t < 7) {
            float wmsum = 0.f;
            for (int s = 0; s < 14; ++s) wmsum += Wm[s];
            float s1 = 0.f;
            for (int e = 0; e < 16; ++e) s1 = fmaf(WcS[t*16+e], bvP[e], s1);
            float p0 = 0.f, p1 = 0.f, p2 = 0.f, p3 = 0.f;
            float q0 = 0.f, q1 = 0.f, q2 = 0.f, q3 = 0.f;
            for (int o = 0; o < 128; o += 4) {
                p0 = fmaf(Wb[t*128+o],   bo[o],   p0);
                p1 = fmaf(Wb[t*128+o+1], bo[o+1], p1);
                p2 = fmaf(Wb[t*128+o+2], bo[o+2], p2);
                p3 = fmaf(Wb[t*128+o+3], bo[o+3], p3);
                q0 += Wb[t*128+o];   q1 += Wb[t*128+o+1];
                q2 += Wb[t*128+o+2]; q3 += Wb[t*128+o+3];
            }
            const float s2 = (p0 + p1) + (p2 + p3);
            const float s3 = (q0 + q1) + (q2 + q3);
            v = wmsum*s1 + wmsum*s2 + bm[0]*s3 + bb[t];
        }
        ws[528 + t] = v * L2E;
        ws[544 + t] = (t < 14) ? Wm[t] * L2E : 0.0f;
    }
}

// ---------------------------------------------------------------------------
// Main kernel. Fragment convention (v_mfma_f32_16x16x16_f16), lane l:
//   col=l&15, q=l>>4;  A[m=col][k=4q+i]  B[k=4q+i][n=col]  D[m=4q+i][n=col]
// 8 batches per wave amortize the per-wave fixed cost (setup + launch/drain);
// launch_bounds(256,4) gives a 128-VGPR budget -> no spill with 8 hoisted
// input vectors. Chains serialized by sched_barrier (r10-proven structure).
// ---------------------------------------------------------------------------
__global__ __launch_bounds__(256, 4) void hop_main(const float* __restrict__ smp,
                                                   const float* __restrict__ W,
                                                   float* __restrict__ out)
{
    const int wave = (blockIdx.x * 256 + threadIdx.x) >> 6;   // 0..NWAVE-1
    const int l    = threadIdx.x & 63;
    const int col  = l & 15;
    const int q    = l >> 4;

    // one-time constant fragments (cached loads: reused by every block)
    const float4 mt  = *reinterpret_cast<const float4*>(W + col*16 + q*4);
    const float4 w2  = *reinterpret_cast<const float4*>(W + 272 + col*16 + q*4);
    const float4 r4  = *reinterpret_cast<const float4*>(W + 256 + q*4);
    const float4 wm4 = *reinterpret_cast<const float4*>(W + 544 + q*4);
    const float  c2_l = W[528 + col];
    const f16x4 mtA  = cvt4(mt.x, mt.y, mt.z, mt.w);
    const f16x4 w2B  = cvt4(w2.x, w2.y, w2.z, w2.w);
    const f16x4 ONE  = {(_Float16)1.0f, (_Float16)1.0f, (_Float16)1.0f, (_Float16)1.0f};
    const f16x4 SIXT = {(_Float16)0.0625f, (_Float16)0.0625f, (_Float16)0.0625f, (_Float16)0.0625f};
    const f32x4 zero = {0.f, 0.f, 0.f, 0.f};
    const f32x4 rC   = {r4.x, r4.y, r4.z, r4.w};
    const f32x4 c2C  = {c2_l, c2_l, c2_l, c2_l};
    const bool  hi   = (q == 3);

    const int srow = (col < 14) ? col : 13;                  // clamp pad rows
    const float* p0 = smp + (size_t)wave * (BPW * 224) + srow * 16 + q * 4;

    auto zbatch = [&](const f32x4& x) -> float {
        // LN stats via reduce-MFMAs (replicated per row)
        const f16x4 xf  = cvt4(x[0], x[1], x[2], x[3]);
        const f16x4 xqf = cvt4(x[0]*x[0], x[1]*x[1], x[2]*x[2], x[3]*x[3]);
        const f32x4 S1 = mfma16(SIXT, xf,  zero);
        const f32x4 S2 = mfma16(SIXT, xqf, zero);
        const float mean = S1[0];
        const float var  = fmaf(-mean, mean, S2[0]);
        const float rstd = __builtin_amdgcn_rsqf(var + 1e-5f);
        const float nmr  = -mean * rstd;
        const f16x4 xhA = cvt4(fmaf(x[0], rstd, nmr), fmaf(x[1], rstd, nmr),
                               fmaf(x[2], rstd, nmr), fmaf(x[3], rstd, nmr));
        // P[key][c] (key in regs) -- independent branch
        const f32x4 P = mfma16(xhA, w2B, zero);
        // T = MT@xh^T + r (log2-scaled), then scores^T (log2 units)
        const f32x4 T  = mfma16(mtA, xhA, rC);
        const f16x4 B2 = cvt4(T[0], T[1], T[2], T[3]);
        const f32x4 SS = mfma16(xhA, B2, zero);
        // exp2 (scores bounded, no max subtraction); kill pad keys 14,15
        const float e0 = __builtin_amdgcn_exp2f(SS[0]);
        const float e1 = __builtin_amdgcn_exp2f(SS[1]);
        const float e2 = hi ? 0.0f : __builtin_amdgcn_exp2f(SS[2]);
        const float e3 = hi ? 0.0f : __builtin_amdgcn_exp2f(SS[3]);
        const f16x4 E  = cvt4(e0, e1, e2, e3);
        const f16x4 Pf = cvt4(P[0], P[1], P[2], P[3]);
        // Zt: E fed as A transposes the reduce -> Z_s lands in the REG dim
        const f32x4 Zt = mfma16(E, ONE, zero);
        const f32x4 G  = mfma16(E, Pf,  zero);    // unnormalized output
        const float w0 = wm4.x * __builtin_amdgcn_rcpf(Zt[0]);
        const float w1 = wm4.y * __builtin_amdgcn_rcpf(Zt[1]);
        const float w2s = wm4.z * __builtin_amdgcn_rcpf(Zt[2]);
        const float w3 = wm4.w * __builtin_amdgcn_rcpf(Zt[3]);
        const f16x4 wA = cvt4(w0, w1, w2s, w3);
        const f16x4 Gf = cvt4(G[0], G[1], G[2], G[3]);
        // z_c = sum_s (wm_s/Z_s) G'[s][c] + const2_c  (log2-scaled)
        const f32x4 ZZ = mfma16(wA, Gf, c2C);
        return ZZ[0];
    };

    // hoist all 8 batch loads (NT streaming, 8 KB in flight per wave)
    f32x4 xv[BPW];
    #pragma unroll
    for (int j = 0; j < BPW; ++j)
        xv[j] = __builtin_nontemporal_load(reinterpret_cast<const f32x4*>(p0 + j * 224));

    const float z0 = zbatch(xv[0]);
    __builtin_amdgcn_sched_barrier(0);
    const float z1 = zbatch(xv[1]);
    __builtin_amdgcn_sched_barrier(0);
    const float z2 = zbatch(xv[2]);
    __builtin_amdgcn_sched_barrier(0);
    const float z3 = zbatch(xv[3]);
    __builtin_amdgcn_sched_barrier(0);
    const float z4 = zbatch(xv[4]);
    __builtin_amdgcn_sched_barrier(0);
    const float z5 = zbatch(xv[5]);
    __builtin_amdgcn_sched_barrier(0);
    const float z6 = zbatch(xv[6]);
    __builtin_amdgcn_sched_barrier(0);
    const float z7 = zbatch(xv[7]);

    // shared softmax7 epilogues: lane-group q handles batch base+q
    auto epilogue = [&](float a0, float a1, float a2, float a3, float* o) {
        float z = (q == 1) ? a1 : a0;
        z = (q == 2) ? a2 : z;
        z = (q == 3) ? a3 : z;
        float e = (col < 7) ? __builtin_amdgcn_exp2f(z) : 0.0f;
        float s = e;
        s += ROR(s, 1); s += ROR(s, 2); s += ROR(s, 4); s += ROR(s, 8);
        if (col < 7) __builtin_nontemporal_store(e * __builtin_amdgcn_rcpf(s), o);
    };
    float* ob = out + ((size_t)wave * BPW + q) * 7 + col;
    epilogue(z0, z1, z2, z3, ob);
    epilogue(z4, z5, z6, z7, ob + 28);
}

extern "C" void kernel_launch(void* const* d_in, const int* in_sizes, int n_in,
                              void* d_out, int out_size, void* d_ws, size_t ws_size,
                              hipStream_t stream) {
    (void)in_sizes; (void)n_in; (void)out_size; (void)ws_size;
    const float* smp = (const float*)d_in[0];
    float* ws = (float*)d_ws;
    hop_prep<<<1, 256, 0, stream>>>(
        (const float*)d_in[1],  (const float*)d_in[2],   // ln_q_g, ln_q_b
        (const float*)d_in[3],                           // ln_k_g
        (const float*)d_in[5],  (const float*)d_in[6],   // ln_v_g, ln_v_b
        (const float*)d_in[7],  (const float*)d_in[8],   // Wq, bq
        (const float*)d_in[9],                           // Wk
        (const float*)d_in[11], (const float*)d_in[12],  // Wv, bv
        (const float*)d_in[13], (const float*)d_in[14],  // Wo, bo
        (const float*)d_in[15], (const float*)d_in[16],  // Wm, bm
        (const float*)d_in[17], (const float*)d_in[18],  // Wb, bb
        ws);
    hop_main<<<NBLK, 256, 0, stream>>>(smp, ws, (float*)d_out);
}